// Round 5
// baseline (128.598 us; speedup 1.0000x reference)
//
#include <hip/hip_runtime.h>

// SSM DPLR kernel: K[h,l] = 2*Re(C_h . dA_h^l . dB_h), dA = diag(g) + q r^T.
// R8 (= R7 + despill): single block per head (grid 256, 16 waves), dual chain
// over shared M128. __launch_bounds__(1024, 4) -> 1 block/CU -> VGPR budget 128,
// so Mk[16]+idmk[16] live in registers (R7's 44-VGPR cap spilled them to scratch:
// FETCH/WRITE doubled, chain steps read M-rows from HBM-backed scratch).
//   l = 64i + j: K[64i+j] = 2 Re( Y_i . X_j ), X_j = dA^j dB.
//   chain A (waves 8..11): Y0_i = C (M128)^i        -> even rows 2i
//   chain B (waves 4..7):  Y1_i = (C M64) (M128)^i  -> odd  rows 2i+1
//   16 barrier'd chain steps (1 seed + 15); ONE setup/serial window.
//   Serial window: wave0 tau128-solve + dual Horner; wave1 sigma+X; producers
//   hoist the cinv divisions.

#define LL 2048

struct C2 { float re, im; };

__device__ __forceinline__ C2 cmul(C2 a, C2 b){ return {a.re*b.re - a.im*b.im, a.re*b.im + a.im*b.re}; }
__device__ __forceinline__ C2 cadd(C2 a, C2 b){ return {a.re+b.re, a.im+b.im}; }
__device__ __forceinline__ C2 csub(C2 a, C2 b){ return {a.re-b.re, a.im-b.im}; }
__device__ __forceinline__ C2 cinv(C2 a){ float s=1.0f/(a.re*a.re+a.im*a.im); return {a.re*s, -a.im*s}; }
__device__ __forceinline__ C2 cscale(float s, C2 a){ return {s*a.re, s*a.im}; }
__device__ __forceinline__ C2 ld2(float2 v){ return {v.x, v.y}; }
__device__ __forceinline__ float2 st2(C2 v){ return make_float2(v.re, v.im); }

template<int CTRL>
__device__ __forceinline__ float dpp_add(float x){
  int t = __builtin_amdgcn_update_dpp(0, __float_as_int(x), CTRL, 0xF, 0xF, true);
  return x + __int_as_float(t);
}
// lane 63 ends with the full 64-lane sum
__device__ __forceinline__ float wave_sum63(float x){
  x = dpp_add<0xB1>(x);   // quad_perm xor1
  x = dpp_add<0x4E>(x);   // quad_perm xor2
  x = dpp_add<0x124>(x);  // row_ror:4
  x = dpp_add<0x128>(x);  // row_ror:8
  x = dpp_add<0x142>(x);  // row_bcast:15
  x = dpp_add<0x143>(x);  // row_bcast:31
  return x;
}
__device__ __forceinline__ float bcast63(float x){
  return __int_as_float(__builtin_amdgcn_readlane(__float_as_int(x), 63));
}
__device__ __forceinline__ float rdlane(float v, int l){
  return __int_as_float(__builtin_amdgcn_readlane(__float_as_int(v), l));
}
// D[m] = S[m-1], lane0 <- 0   (wave_shr:1 = 0x138)
__device__ __forceinline__ float shr1(float x){
  return __int_as_float(__builtin_amdgcn_update_dpp(0, __float_as_int(x), 0x138, 0xF, 0xF, true));
}
// insert scalar s (SGPR, from readlane) into lane 0 of v: v_cndmask
__device__ __forceinline__ float ins0(float v, float s, int lane){
  return (lane == 0) ? s : v;
}

// 2-wide triangular-Toeplitz solve (length 64): v_j = rhs_j + sum_{i<j} w_{j-1-i} v_i.
__device__ __forceinline__ void tri_solve64(const C2 wl, C2 va, const int lane,
                                            float& so_re, float& so_im)
{
    C2 wsh = { shr1(wl.re), shr1(wl.im) };      // w_{m-1}, lane0 = 0
    const float w0r = rdlane(wl.re, 0);
    const float w0i = rdlane(wl.im, 0);
    so_re = 0.0f; so_im = 0.0f;
    for (int j = 0; j < 64; j += 2) {
        const float s0r = rdlane(va.re, j);
        const float s0i = rdlane(va.im, j);
        const float v1r = rdlane(va.re, j + 1);
        const float v1i = rdlane(va.im, j + 1);
        const float s1r = v1r + (w0r*s0r - w0i*s0i);
        const float s1i = v1i + (w0r*s0i + w0i*s0r);
        if (lane == j)     { so_re = s0r; so_im = s0i; }
        if (lane == j + 1) { so_re = s1r; so_im = s1i; }
        const C2 wsh1 = { shr1(wsh.re), shr1(wsh.im) };   // w_{m-2-j}
        va.re += wsh.re*s0r - wsh.im*s0i;
        va.im += wsh.re*s0i + wsh.im*s0r;
        va.re += wsh1.re*s1r - wsh1.im*s1i;
        va.im += wsh1.re*s1i + wsh1.im*s1r;
        wsh.re = shr1(wsh1.re);
        wsh.im = shr1(wsh1.im);
    }
}

// 2-wide extended solve (length 128): state split lo (j=0..63) / hi (j=64..127).
// On return: tlo lane j = tau_j, thi lane c = tau_{64+c}.
__device__ __forceinline__ void tri_solve128(const C2 wlo, const C2 whi, const int lane,
                                             C2& tlo, C2& thi)
{
    C2 valo = wlo, vahi = whi;                  // rhs = w (tau solve)
    C2 wsl = { shr1(wlo.re), shr1(wlo.im) };    // w_{m-1}
    C2 wsh;                                     // w_{63+m'}
    {
        const float br = rdlane(wlo.re, 63), bi = rdlane(wlo.im, 63);
        wsh.re = ins0(shr1(whi.re), br, lane);
        wsh.im = ins0(shr1(whi.im), bi, lane);
    }
    const float w0r = rdlane(wlo.re, 0);
    const float w0i = rdlane(wlo.im, 0);
    tlo = {0,0}; thi = {0,0};
    // lo region: sources j = 0..63
    for (int j = 0; j < 64; j += 2) {
        const float s0r = rdlane(valo.re, j);
        const float s0i = rdlane(valo.im, j);
        const float v1r = rdlane(valo.re, j + 1);
        const float v1i = rdlane(valo.im, j + 1);
        const float s1r = v1r + (w0r*s0r - w0i*s0i);
        const float s1i = v1i + (w0r*s0i + w0i*s0r);
        if (lane == j)     { tlo.re = s0r; tlo.im = s0i; }
        if (lane == j + 1) { tlo.re = s1r; tlo.im = s1i; }
        // shifted coefficient registers for source j+1
        const C2 wsl1 = { shr1(wsl.re), shr1(wsl.im) };           // w_{m-2-j}
        C2 wsh1;
        {
            const float br = rdlane(wsl.re, 63), bi = rdlane(wsl.im, 63);  // w_{62-j}
            wsh1.re = ins0(shr1(wsh.re), br, lane);
            wsh1.im = ins0(shr1(wsh.im), bi, lane);
        }
        valo.re += wsl.re*s0r - wsl.im*s0i + wsl1.re*s1r - wsl1.im*s1i;
        valo.im += wsl.re*s0i + wsl.im*s0r + wsl1.re*s1i + wsl1.im*s1r;
        vahi.re += wsh.re*s0r - wsh.im*s0i + wsh1.re*s1r - wsh1.im*s1i;
        vahi.im += wsh.re*s0i + wsh.im*s0r + wsh1.re*s1i + wsh1.im*s1r;
        // advance by 2
        wsl.re = shr1(wsl1.re); wsl.im = shr1(wsl1.im);
        {
            const float br = rdlane(wsl1.re, 63), bi = rdlane(wsl1.im, 63); // w_{61-j}
            wsh.re = ins0(shr1(wsh1.re), br, lane);
            wsh.im = ins0(shr1(wsh1.im), bi, lane);
        }
    }
    // hi region: sources j = 64..127; lo coefficients exhausted, shift-ins are 0.
    for (int j = 64; j < 128; j += 2) {
        const int jr = j - 64;
        const float s0r = rdlane(vahi.re, jr);
        const float s0i = rdlane(vahi.im, jr);
        const float v1r = rdlane(vahi.re, jr + 1);
        const float v1i = rdlane(vahi.im, jr + 1);
        const float s1r = v1r + (w0r*s0r - w0i*s0i);
        const float s1i = v1i + (w0r*s0i + w0i*s0r);
        if (lane == jr)     { thi.re = s0r; thi.im = s0i; }
        if (lane == jr + 1) { thi.re = s1r; thi.im = s1i; }
        const C2 wsh1 = { shr1(wsh.re), shr1(wsh.im) };
        vahi.re += wsh.re*s0r - wsh.im*s0i + wsh1.re*s1r - wsh1.im*s1i;
        vahi.im += wsh.re*s0i + wsh.im*s0r + wsh1.re*s1i + wsh1.im*s1r;
        wsh.re = shr1(wsh1.re);
        wsh.im = shr1(wsh1.im);
    }
}

__global__ __launch_bounds__(1024, 4) void ssm_dplr_kernel(
    const float* __restrict__ A_real, const float* __restrict__ A_imag,
    const float* __restrict__ B_real, const float* __restrict__ B_imag,
    const float* __restrict__ P_real, const float* __restrict__ P_imag,
    const float* __restrict__ C_real, const float* __restrict__ C_imag,
    const float* __restrict__ log_dt, float* __restrict__ out)
{
    const int h    = blockIdx.x;
    const int t    = threadIdx.x;
    const int lane = t & 63;
    const int wid  = t >> 6;         // wave 0..15

    extern __shared__ char sm[];
    float2* Abuf = (float2*)sm;               // 64x64: G (powers), later X  [32 KB]
    float2* Cs   = (float2*)(sm + 32768);     // 32x64 Y rows                [16 KB]
    float2* prt  = (float2*)(sm + 49152);     // 2 x (8x64) chain partials   [ 8 KB]
    // transpose-sum partials alias Cs + prt (dead at that phase):
    float2* tw   = (float2*)(sm + 32768);     // 16x64
    float2* ta   = (float2*)(sm + 40960);     // 16x64
    float2* te   = (float2*)(sm + 49152);     // 16x64 (= prt, dead then)
    float2* gA   = (float2*)(sm + 57344);     // smalls, 64 float2 each:
    float2* qA   = gA + 64;
    float2* g64A = gA + 128;
    float2* TgA  = gA + 192;   // T64(g)
    float2* TpA  = gA + 256;   // T64'(g)
    float2* T1gA = gA + 320;   // T128(g)
    float2* T1pA = gA + 384;   // T128'(g)
    float2* rqA  = gA + 448;
    float2* rxA  = gA + 512;
    float2* reA  = gA + 576;   // rq * g64
    float2* wvA  = gA + 640;   // w_0..63
    float2* avA  = gA + 704;   // a_0..63
    float2* weA  = gA + 768;   // w_64..127
    // LDS total: 57344 + 13*512 = 64000 B  (<= 64 KB dynamic limit)

    // ---------------- setup (every wave redundantly, per-lane n = lane) ----------------
    const int idx = h * 64 + lane;
    const float dt = expf(log_dt[h]);
    const float c  = 0.5f * dt;

    const C2 lam = { -A_real[idx], -A_imag[idx] };
    const C2 p   = {  P_real[idx],  P_imag[idx] };
    const C2 Bv  = {  B_real[idx],  B_imag[idx] };
    const C2 Cv  = {  C_real[idx],  C_imag[idx] };
    const C2 pc  = { p.re, -p.im };

    const C2 d = cinv(C2{ 1.0f - c*lam.re, -c*lam.im });
    const C2 g = cmul(d, C2{ 1.0f + c*lam.re, c*lam.im });   // diag of dA

    // Sherman-Morrison scalars via DPP wave sums
    C2 sv = cscale(p.re*p.re + p.im*p.im, d);
    C2 uv = cmul(cmul(d, pc), Bv);
    sv.re = bcast63(wave_sum63(sv.re)); sv.im = bcast63(wave_sum63(sv.im));
    uv.re = bcast63(wave_sum63(uv.re)); uv.im = bcast63(wave_sum63(uv.im));

    const C2 beta  = cscale(c, cinv(C2{ 1.0f + c*sv.re, c*sv.im }));
    const C2 bs    = cmul(beta, sv);
    const C2 gamma = { -c*(1.0f - bs.re), c*bs.im };

    const C2 q  = cmul(d, p);
    const C2 r  = cmul(pc, csub(gamma, cmul(beta, g)));
    const C2 x0 = cscale(dt, csub(cmul(d, Bv), cmul(cmul(beta, uv), q)));  // dB

    // power chain
    const C2 g2  = cmul(g,  g);
    const C2 g4  = cmul(g2, g2);
    const C2 g8  = cmul(g4, g4);
    const C2 g16 = cmul(g8, g8);
    const C2 g32 = cmul(g16,g16);
    const C2 g64 = cmul(g32,g32);

    if (wid == 0) {
        const C2 rq = cmul(r, q);
        gA[lane]   = st2(g);
        qA[lane]   = st2(q);
        g64A[lane] = st2(g64);
        rqA[lane]  = st2(rq);
        rxA[lane]  = st2(cmul(r, x0));
        reA[lane]  = st2(cmul(rq, g64));
    }
    __syncthreads();

    // ---------------- G-gen: G[j][n] = g_n^j, rows j in [4w, 4w+4) ----------------
    {
        C2 cur = {1.0f, 0.0f};
        if (wid & 1) cur = g4;
        if (wid & 2) cur = cmul(cur, g8);
        if (wid & 4) cur = cmul(cur, g16);
        if (wid & 8) cur = cmul(cur, g32);          // g^(4*wid)
        #pragma unroll
        for (int jj = 0; jj < 4; ++jj) {
            const int j = 4*wid + jj;
            Abuf[j*64 + ((lane + j) & 63)] = st2(cur);   // rotated columns
            cur = cmul(cur, g);
        }
    }
    __syncthreads();

    // ---------------- w_j, a_j, we_j (=w_{64+j}) via transpose-sum (lane = j) ----------------
    {
        C2 accw = {0,0}, acca = {0,0}, acce = {0,0};
        #pragma unroll
        for (int kk = 0; kk < 4; ++kk) {
            const int n = 4*wid + kk;
            const C2 Gv = ld2(Abuf[lane*64 + ((n + lane) & 63)]);
            const C2 fq = ld2(rqA[n]);      // uniform
            const C2 fx = ld2(rxA[n]);      // uniform
            const C2 fe = ld2(reA[n]);      // uniform
            accw = cadd(accw, cmul(Gv, fq));
            acca = cadd(acca, cmul(Gv, fx));
            acce = cadd(acce, cmul(Gv, fe));
        }
        tw[wid*64 + lane] = st2(accw);
        ta[wid*64 + lane] = st2(acca);
        te[wid*64 + lane] = st2(acce);
    }
    __syncthreads();
    if (t < 64) {
        C2 sw = {0,0}, sa = {0,0}, se = {0,0};
        #pragma unroll
        for (int w2 = 0; w2 < 16; ++w2) {
            sw = cadd(sw, ld2(tw[w2*64 + t]));
            sa = cadd(sa, ld2(ta[w2*64 + t]));
            se = cadd(se, ld2(te[w2*64 + t]));
        }
        wvA[t] = st2(sw);
        avA[t] = st2(sa);
        weA[t] = st2(se);
    }
    __syncthreads();

    // ---------------- serial window ----------------
    // wave0: tau-solve (length 128) + dual Horner -> T64/T64'/T128/T128'
    // wave1: sigma-solve + X rebuild
    // waves 4..11 (producers): hoist divisions (idmk, g63d); wave12: seed Cs[0]=C
    const bool isB = (wid >= 4 && wid < 8);    // chain B: odd rows, seeds with M64
    const bool isA = (wid >= 8 && wid < 12);   // chain A: even rows
    const int  cw  = isA ? (wid - 8) : (wid - 4);   // producer index 0..3
    C2 idmk[16];
    C2 g63d = {0,0};

    if (wid == 0) {
        C2 tlo, thi;
        tri_solve128(ld2(wvA[lane]), ld2(weA[lane]), lane, tlo, thi);
        // P-Horner over tau_0..62 ; Q-Horner over tau_63..126 (interleaved chains)
        C2 pp = { rdlane(tlo.re, 0),  rdlane(tlo.im, 0)  };
        C2 dd = {0,0};
        C2 qq = { rdlane(tlo.re, 63), rdlane(tlo.im, 63) };   // tau_63
        C2 qd = {0,0};
        for (int i = 1; i <= 63; ++i) {
            if (i <= 62) {
                const C2 ti = { rdlane(tlo.re, i), rdlane(tlo.im, i) };
                dd = cadd(cmul(dd, g), pp);
                pp = cadd(cmul(pp, g), ti);
            }
            const C2 tq = { rdlane(thi.re, i-1), rdlane(thi.im, i-1) };  // tau_{63+i}
            qd = cadd(cmul(qd, g), qq);
            qq = cadd(cmul(qq, g), tq);
        }
        const C2 T64v = cmul(g, pp);              // T64(g)
        const C2 T64d = cadd(pp, cmul(g, dd));    // T64'(g)
        // T128(z) = z^64 T64(z) + z Q(z);  T128' = 64 z^63 T64 + z^64 T64' + Q + z Q'
        const C2 g63   = cmul(g64, cinv(g));
        const C2 T128v = cadd(cmul(g64, T64v), cmul(g, qq));
        const C2 T128d = cadd(cadd(cscale(64.0f, cmul(g63, T64v)), cmul(g64, T64d)),
                              cadd(qq, cmul(g, qd)));
        TgA[lane]  = st2(T64v);
        TpA[lane]  = st2(T64d);
        T1gA[lane] = st2(T128v);
        T1pA[lane] = st2(T128d);
    } else if (wid == 1) {
        float sg_re, sg_im;
        tri_solve64(ld2(wvA[lane]), ld2(avA[lane]), lane, sg_re, sg_im);   // sigma
        // X_0 = dB; X_{j+1} = g.*X_j + sigma_j * q
        C2 x = x0;
        for (int j = 0; j < 64; ++j) {
            Abuf[j*64 + ((lane + j) & 63)] = st2(x);
            const float sjr = rdlane(sg_re, j);
            const float sji = rdlane(sg_im, j);
            const float nr = g.re*x.re - g.im*x.im + sjr*q.re - sji*q.im;
            const float ni = g.re*x.im + g.im*x.re + sjr*q.im + sji*q.re;
            x.re = nr; x.im = ni;
        }
    } else if (isA || isB) {
        // hoist the divisions for this producer's 16 M-rows
        #pragma unroll
        for (int k = 0; k < 16; ++k) {
            const int n = 16*cw + k;
            const C2 gn = ld2(gA[n]);              // uniform
            idmk[k] = cinv(csub(gn, g));           // n==lane -> inf/NaN, diag overwritten
        }
        g63d = cmul(g64, cinv(g));                 // g^63
    } else if (wid == 12) {
        Cs[lane] = st2(Cv);                        // row 0: Y0_0 = C
    }
    __syncthreads();

    // ---------------- M build (closed form, power t = 64 or 128) ----------------
    // M_t[n][m] = d_nm g^t_n + q_n r_m [ (g^t_n - g^t_m) + (T_t(g_n)-T_t(g_m)) ] / (g_n - g_m)
    // M_t[n][n] = g^t_n + q_n r_n ( t g_n^{t-1} + T_t'(g_n) )
    C2 Mk[16];
    auto buildM = [&](bool p128){
        const C2 gt  = p128 ? cmul(g64, g64) : g64;                         // g^t (lane m)
        const C2 Ttm = p128 ? ld2(T1gA[lane]) : ld2(TgA[lane]);
        #pragma unroll
        for (int k = 0; k < 16; ++k) {
            const int n = 16*cw + k;
            const C2 qn   = ld2(qA[n]);            // uniform reads
            const C2 g64n = ld2(g64A[n]);
            const C2 gtn  = p128 ? cmul(g64n, g64n) : g64n;
            const C2 Ttn  = p128 ? ld2(T1gA[n]) : ld2(TgA[n]);
            const C2 num  = cmul(r, cadd(csub(gtn, gt), csub(Ttn, Ttm)));
            Mk[k] = cmul(cmul(qn, num), idmk[k]);
        }
        if ((lane >> 4) == cw) {                   // diagonal element owned by this thread
            const int k0 = lane & 15;
            const C2 Tp   = p128 ? ld2(T1pA[lane]) : ld2(TpA[lane]);
            const C2 gtm1 = p128 ? cmul(g64, g63d) : g63d;    // g^{t-1}
            const C2 S    = cmul(r, cadd(cscale(p128 ? 128.0f : 64.0f, gtm1), Tp));
            Mk[k0] = cadd(gt, cmul(q, S));
        }
    };

    // matvec: acc[m] = sum_k Yin[16cw+k] * Mk[k][m], write partial
    auto chainStep = [&](const C2 Yin, int buf, int base){
        C2 acc = {0,0};
        #pragma unroll
        for (int k = 0; k < 16; ++k) {
            const float cr  = rdlane(Yin.re, 16*cw + k);
            const float cim = rdlane(Yin.im, 16*cw + k);
            acc.re += cr*Mk[k].re - cim*Mk[k].im;
            acc.im += cr*Mk[k].im + cim*Mk[k].re;
        }
        prt[buf*512 + base + cw*64 + lane] = st2(acc);
    };
    auto chainReduce = [&](int buf, int base) -> C2 {
        C2 nc = {0,0};
        #pragma unroll
        for (int w2 = 0; w2 < 4; ++w2) {
            const float2 pv = prt[buf*512 + base + w2*64 + lane];
            nc.re += pv.x; nc.im += pv.y;
        }
        return nc;
    };

    C2 Ci = Cv;
    // pre-step: chain B seeds Y1_0 = C . M64 (buf 0); chain A builds M128
    if (isB) {
        buildM(false);                  // M64 rows
        chainStep(Cv, 0, 256);
    } else if (isA) {
        buildM(true);                   // M128 rows
    }
    __syncthreads();
    if (isB) {
        Ci = chainReduce(0, 256);
        if (wid == 4) Cs[1*64 + lane] = st2(Ci);   // row 1
        buildM(true);                   // rebuild as M128
    }

    // main chain: steps s = 1..15
    for (int s = 1; s <= 15; ++s) {
        const int buf = s & 1;
        if (isA) chainStep(Ci, buf, 0);
        if (isB) chainStep(Ci, buf, 256);
        __syncthreads();
        if (isA) {
            Ci = chainReduce(buf, 0);
            if (wid == 8) Cs[(2*s)*64 + lane] = st2(Ci);       // even row
        }
        if (isB) {
            Ci = chainReduce(buf, 256);
            if (wid == 4) Cs[(2*s + 1)*64 + lane] = st2(Ci);   // odd row
        }
    }
    __syncthreads();

    // ---------------- output: rows r0 = 2*wid, r1 = 2*wid+1 ----------------
    {
        const int r0 = 2*wid, r1 = 2*wid + 1;
        float a0 = 0.0f, a1 = 0.0f;
        #pragma unroll 8
        for (int n = 0; n < 64; ++n) {
            const float2 xv = Abuf[lane*64 + ((n + lane) & 63)];
            const float2 c0 = Cs[r0*64 + n];    // uniform
            const float2 c1 = Cs[r1*64 + n];    // uniform
            a0 += c0.x*xv.x - c0.y*xv.y;
            a1 += c1.x*xv.x - c1.y*xv.y;
        }
        float* outh = out + h * LL;
        outh[r0*64 + lane] = 2.0f * a0;
        outh[r1*64 + lane] = 2.0f * a1;
    }
}

extern "C" void kernel_launch(void* const* d_in, const int* in_sizes, int n_in,
                              void* d_out, int out_size, void* d_ws, size_t ws_size,
                              hipStream_t stream) {
    const float* A_real = (const float*)d_in[0];
    const float* A_imag = (const float*)d_in[1];
    const float* B_real = (const float*)d_in[2];
    const float* B_imag = (const float*)d_in[3];
    const float* P_real = (const float*)d_in[4];
    const float* P_imag = (const float*)d_in[5];
    const float* C_real = (const float*)d_in[6];
    const float* C_imag = (const float*)d_in[7];
    const float* log_dt = (const float*)d_in[8];
    float* out = (float*)d_out;

    const size_t lds = 57344 + 13*64*sizeof(float2);   // 64000 B
    ssm_dplr_kernel<<<256, 1024, lds, stream>>>(
        A_real, A_imag, B_real, B_imag, P_real, P_imag,
        C_real, C_imag, log_dt, out);
}

// Round 6
// 127.555 us; speedup vs baseline: 1.0082x; 1.0082x over previous
//
#include <hip/hip_runtime.h>

// SSM DPLR kernel: K[h,l] = 2*Re(C_h . dA_h^l . dB_h), dA = diag(g) + q r^T.
// R9 (= R7 despilled): single block per head (grid 256, 16 waves), dual chain
// over shared M128. Spill fix, two levers:
//   (1) no idmk[16] hoist -- cinv computed inline in buildM (R6b-verified form),
//       register demand ~60 < 64-cap;
//   (2) amdgpu_waves_per_eu(4,4) pins 4 waves/EU -> VGPR budget 128
//       (launch_bounds' 2nd arg is only a MINIMUM; compiler targeted 8/EU and
//        spilled Mk[16]+idmk[16] to scratch: R7/R8 FETCH/WRITE 2x, VGPR=44).
//   l = 64i + j: K[64i+j] = 2 Re( Y_i . X_j ), X_j = dA^j dB.
//   chain A (waves 8..11): Y0_i = C (M128)^i        -> even rows 2i
//   chain B (waves 4..7):  Y1_i = (C M64) (M128)^i  -> odd  rows 2i+1
//   16 barrier'd chain steps (1 seed + 15); ONE setup/serial window.
//   Serial window: wave0 tau128-solve + dual Horner; wave1 sigma+X.

#define LL 2048

struct C2 { float re, im; };

__device__ __forceinline__ C2 cmul(C2 a, C2 b){ return {a.re*b.re - a.im*b.im, a.re*b.im + a.im*b.re}; }
__device__ __forceinline__ C2 cadd(C2 a, C2 b){ return {a.re+b.re, a.im+b.im}; }
__device__ __forceinline__ C2 csub(C2 a, C2 b){ return {a.re-b.re, a.im-b.im}; }
__device__ __forceinline__ C2 cinv(C2 a){ float s=1.0f/(a.re*a.re+a.im*a.im); return {a.re*s, -a.im*s}; }
__device__ __forceinline__ C2 cscale(float s, C2 a){ return {s*a.re, s*a.im}; }
__device__ __forceinline__ C2 ld2(float2 v){ return {v.x, v.y}; }
__device__ __forceinline__ float2 st2(C2 v){ return make_float2(v.re, v.im); }

template<int CTRL>
__device__ __forceinline__ float dpp_add(float x){
  int t = __builtin_amdgcn_update_dpp(0, __float_as_int(x), CTRL, 0xF, 0xF, true);
  return x + __int_as_float(t);
}
// lane 63 ends with the full 64-lane sum
__device__ __forceinline__ float wave_sum63(float x){
  x = dpp_add<0xB1>(x);   // quad_perm xor1
  x = dpp_add<0x4E>(x);   // quad_perm xor2
  x = dpp_add<0x124>(x);  // row_ror:4
  x = dpp_add<0x128>(x);  // row_ror:8
  x = dpp_add<0x142>(x);  // row_bcast:15
  x = dpp_add<0x143>(x);  // row_bcast:31
  return x;
}
__device__ __forceinline__ float bcast63(float x){
  return __int_as_float(__builtin_amdgcn_readlane(__float_as_int(x), 63));
}
__device__ __forceinline__ float rdlane(float v, int l){
  return __int_as_float(__builtin_amdgcn_readlane(__float_as_int(v), l));
}
// D[m] = S[m-1], lane0 <- 0   (wave_shr:1 = 0x138)
__device__ __forceinline__ float shr1(float x){
  return __int_as_float(__builtin_amdgcn_update_dpp(0, __float_as_int(x), 0x138, 0xF, 0xF, true));
}
// insert scalar s (SGPR, from readlane) into lane 0 of v: v_cndmask
__device__ __forceinline__ float ins0(float v, float s, int lane){
  return (lane == 0) ? s : v;
}

// 2-wide triangular-Toeplitz solve (length 64): v_j = rhs_j + sum_{i<j} w_{j-1-i} v_i.
__device__ __forceinline__ void tri_solve64(const C2 wl, C2 va, const int lane,
                                            float& so_re, float& so_im)
{
    C2 wsh = { shr1(wl.re), shr1(wl.im) };      // w_{m-1}, lane0 = 0
    const float w0r = rdlane(wl.re, 0);
    const float w0i = rdlane(wl.im, 0);
    so_re = 0.0f; so_im = 0.0f;
    for (int j = 0; j < 64; j += 2) {
        const float s0r = rdlane(va.re, j);
        const float s0i = rdlane(va.im, j);
        const float v1r = rdlane(va.re, j + 1);
        const float v1i = rdlane(va.im, j + 1);
        const float s1r = v1r + (w0r*s0r - w0i*s0i);
        const float s1i = v1i + (w0r*s0i + w0i*s0r);
        if (lane == j)     { so_re = s0r; so_im = s0i; }
        if (lane == j + 1) { so_re = s1r; so_im = s1i; }
        const C2 wsh1 = { shr1(wsh.re), shr1(wsh.im) };   // w_{m-2-j}
        va.re += wsh.re*s0r - wsh.im*s0i;
        va.im += wsh.re*s0i + wsh.im*s0r;
        va.re += wsh1.re*s1r - wsh1.im*s1i;
        va.im += wsh1.re*s1i + wsh1.im*s1r;
        wsh.re = shr1(wsh1.re);
        wsh.im = shr1(wsh1.im);
    }
}

// 2-wide extended solve (length 128): state split lo (j=0..63) / hi (j=64..127).
// On return: tlo lane j = tau_j, thi lane c = tau_{64+c}.
__device__ __forceinline__ void tri_solve128(const C2 wlo, const C2 whi, const int lane,
                                             C2& tlo, C2& thi)
{
    C2 valo = wlo, vahi = whi;                  // rhs = w (tau solve)
    C2 wsl = { shr1(wlo.re), shr1(wlo.im) };    // w_{m-1}
    C2 wsh;                                     // w_{63+m'}
    {
        const float br = rdlane(wlo.re, 63), bi = rdlane(wlo.im, 63);
        wsh.re = ins0(shr1(whi.re), br, lane);
        wsh.im = ins0(shr1(whi.im), bi, lane);
    }
    const float w0r = rdlane(wlo.re, 0);
    const float w0i = rdlane(wlo.im, 0);
    tlo = {0,0}; thi = {0,0};
    // lo region: sources j = 0..63
    for (int j = 0; j < 64; j += 2) {
        const float s0r = rdlane(valo.re, j);
        const float s0i = rdlane(valo.im, j);
        const float v1r = rdlane(valo.re, j + 1);
        const float v1i = rdlane(valo.im, j + 1);
        const float s1r = v1r + (w0r*s0r - w0i*s0i);
        const float s1i = v1i + (w0r*s0i + w0i*s0r);
        if (lane == j)     { tlo.re = s0r; tlo.im = s0i; }
        if (lane == j + 1) { tlo.re = s1r; tlo.im = s1i; }
        // shifted coefficient registers for source j+1
        const C2 wsl1 = { shr1(wsl.re), shr1(wsl.im) };           // w_{m-2-j}
        C2 wsh1;
        {
            const float br = rdlane(wsl.re, 63), bi = rdlane(wsl.im, 63);  // w_{62-j}
            wsh1.re = ins0(shr1(wsh.re), br, lane);
            wsh1.im = ins0(shr1(wsh.im), bi, lane);
        }
        valo.re += wsl.re*s0r - wsl.im*s0i + wsl1.re*s1r - wsl1.im*s1i;
        valo.im += wsl.re*s0i + wsl.im*s0r + wsl1.re*s1i + wsl1.im*s1r;
        vahi.re += wsh.re*s0r - wsh.im*s0i + wsh1.re*s1r - wsh1.im*s1i;
        vahi.im += wsh.re*s0i + wsh.im*s0r + wsh1.re*s1i + wsh1.im*s1r;
        // advance by 2
        wsl.re = shr1(wsl1.re); wsl.im = shr1(wsl1.im);
        {
            const float br = rdlane(wsl1.re, 63), bi = rdlane(wsl1.im, 63); // w_{61-j}
            wsh.re = ins0(shr1(wsh1.re), br, lane);
            wsh.im = ins0(shr1(wsh1.im), bi, lane);
        }
    }
    // hi region: sources j = 64..127; lo coefficients exhausted, shift-ins are 0.
    for (int j = 64; j < 128; j += 2) {
        const int jr = j - 64;
        const float s0r = rdlane(vahi.re, jr);
        const float s0i = rdlane(vahi.im, jr);
        const float v1r = rdlane(vahi.re, jr + 1);
        const float v1i = rdlane(vahi.im, jr + 1);
        const float s1r = v1r + (w0r*s0r - w0i*s0i);
        const float s1i = v1i + (w0r*s0i + w0i*s0r);
        if (lane == jr)     { thi.re = s0r; thi.im = s0i; }
        if (lane == jr + 1) { thi.re = s1r; thi.im = s1i; }
        const C2 wsh1 = { shr1(wsh.re), shr1(wsh.im) };
        vahi.re += wsh.re*s0r - wsh.im*s0i + wsh1.re*s1r - wsh1.im*s1i;
        vahi.im += wsh.re*s0i + wsh.im*s0r + wsh1.re*s1i + wsh1.im*s1r;
        wsh.re = shr1(wsh1.re);
        wsh.im = shr1(wsh1.im);
    }
}

__global__ __launch_bounds__(1024)
__attribute__((amdgpu_waves_per_eu(4, 4)))
void ssm_dplr_kernel(
    const float* __restrict__ A_real, const float* __restrict__ A_imag,
    const float* __restrict__ B_real, const float* __restrict__ B_imag,
    const float* __restrict__ P_real, const float* __restrict__ P_imag,
    const float* __restrict__ C_real, const float* __restrict__ C_imag,
    const float* __restrict__ log_dt, float* __restrict__ out)
{
    const int h    = blockIdx.x;
    const int t    = threadIdx.x;
    const int lane = t & 63;
    const int wid  = t >> 6;         // wave 0..15

    extern __shared__ char sm[];
    float2* Abuf = (float2*)sm;               // 64x64: G (powers), later X  [32 KB]
    float2* Cs   = (float2*)(sm + 32768);     // 32x64 Y rows                [16 KB]
    float2* prt  = (float2*)(sm + 49152);     // 2 x (8x64) chain partials   [ 8 KB]
    // transpose-sum partials alias Cs + prt (dead at that phase):
    float2* tw   = (float2*)(sm + 32768);     // 16x64
    float2* ta   = (float2*)(sm + 40960);     // 16x64
    float2* te   = (float2*)(sm + 49152);     // 16x64 (= prt, dead then)
    float2* gA   = (float2*)(sm + 57344);     // smalls, 64 float2 each:
    float2* qA   = gA + 64;
    float2* g64A = gA + 128;
    float2* TgA  = gA + 192;   // T64(g)
    float2* TpA  = gA + 256;   // T64'(g)
    float2* T1gA = gA + 320;   // T128(g)
    float2* T1pA = gA + 384;   // T128'(g)
    float2* rqA  = gA + 448;
    float2* rxA  = gA + 512;
    float2* reA  = gA + 576;   // rq * g64
    float2* wvA  = gA + 640;   // w_0..63
    float2* avA  = gA + 704;   // a_0..63
    float2* weA  = gA + 768;   // w_64..127
    // LDS total: 57344 + 13*512 = 64000 B  (<= 64 KB dynamic limit)

    // ---------------- setup (every wave redundantly, per-lane n = lane) ----------------
    const int idx = h * 64 + lane;
    const float dt = expf(log_dt[h]);
    const float c  = 0.5f * dt;

    const C2 lam = { -A_real[idx], -A_imag[idx] };
    const C2 p   = {  P_real[idx],  P_imag[idx] };
    const C2 Bv  = {  B_real[idx],  B_imag[idx] };
    const C2 Cv  = {  C_real[idx],  C_imag[idx] };
    const C2 pc  = { p.re, -p.im };

    const C2 d = cinv(C2{ 1.0f - c*lam.re, -c*lam.im });
    const C2 g = cmul(d, C2{ 1.0f + c*lam.re, c*lam.im });   // diag of dA

    // Sherman-Morrison scalars via DPP wave sums
    C2 sv = cscale(p.re*p.re + p.im*p.im, d);
    C2 uv = cmul(cmul(d, pc), Bv);
    sv.re = bcast63(wave_sum63(sv.re)); sv.im = bcast63(wave_sum63(sv.im));
    uv.re = bcast63(wave_sum63(uv.re)); uv.im = bcast63(wave_sum63(uv.im));

    const C2 beta  = cscale(c, cinv(C2{ 1.0f + c*sv.re, c*sv.im }));
    const C2 bs    = cmul(beta, sv);
    const C2 gamma = { -c*(1.0f - bs.re), c*bs.im };

    const C2 q  = cmul(d, p);
    const C2 r  = cmul(pc, csub(gamma, cmul(beta, g)));
    const C2 x0 = cscale(dt, csub(cmul(d, Bv), cmul(cmul(beta, uv), q)));  // dB

    // power chain
    const C2 g2  = cmul(g,  g);
    const C2 g4  = cmul(g2, g2);
    const C2 g8  = cmul(g4, g4);
    const C2 g16 = cmul(g8, g8);
    const C2 g32 = cmul(g16,g16);
    const C2 g64 = cmul(g32,g32);

    if (wid == 0) {
        const C2 rq = cmul(r, q);
        gA[lane]   = st2(g);
        qA[lane]   = st2(q);
        g64A[lane] = st2(g64);
        rqA[lane]  = st2(rq);
        rxA[lane]  = st2(cmul(r, x0));
        reA[lane]  = st2(cmul(rq, g64));
    }
    __syncthreads();

    // ---------------- G-gen: G[j][n] = g_n^j, rows j in [4w, 4w+4) ----------------
    {
        C2 cur = {1.0f, 0.0f};
        if (wid & 1) cur = g4;
        if (wid & 2) cur = cmul(cur, g8);
        if (wid & 4) cur = cmul(cur, g16);
        if (wid & 8) cur = cmul(cur, g32);          // g^(4*wid)
        #pragma unroll
        for (int jj = 0; jj < 4; ++jj) {
            const int j = 4*wid + jj;
            Abuf[j*64 + ((lane + j) & 63)] = st2(cur);   // rotated columns
            cur = cmul(cur, g);
        }
    }
    __syncthreads();

    // ---------------- w_j, a_j, we_j (=w_{64+j}) via transpose-sum (lane = j) ----------------
    {
        C2 accw = {0,0}, acca = {0,0}, acce = {0,0};
        #pragma unroll
        for (int kk = 0; kk < 4; ++kk) {
            const int n = 4*wid + kk;
            const C2 Gv = ld2(Abuf[lane*64 + ((n + lane) & 63)]);
            const C2 fq = ld2(rqA[n]);      // uniform
            const C2 fx = ld2(rxA[n]);      // uniform
            const C2 fe = ld2(reA[n]);      // uniform
            accw = cadd(accw, cmul(Gv, fq));
            acca = cadd(acca, cmul(Gv, fx));
            acce = cadd(acce, cmul(Gv, fe));
        }
        tw[wid*64 + lane] = st2(accw);
        ta[wid*64 + lane] = st2(acca);
        te[wid*64 + lane] = st2(acce);
    }
    __syncthreads();
    if (t < 64) {
        C2 sw = {0,0}, sa = {0,0}, se = {0,0};
        #pragma unroll
        for (int w2 = 0; w2 < 16; ++w2) {
            sw = cadd(sw, ld2(tw[w2*64 + t]));
            sa = cadd(sa, ld2(ta[w2*64 + t]));
            se = cadd(se, ld2(te[w2*64 + t]));
        }
        wvA[t] = st2(sw);
        avA[t] = st2(sa);
        weA[t] = st2(se);
    }
    __syncthreads();

    // ---------------- serial window ----------------
    // wave0: tau-solve (length 128) + dual Horner -> T64/T64'/T128/T128'
    // wave1: sigma-solve + X rebuild;  wave12: seed Cs[0]=C
    const bool isB = (wid >= 4 && wid < 8);    // chain B: odd rows, seeds with M64
    const bool isA = (wid >= 8 && wid < 12);   // chain A: even rows
    const int  cw  = isA ? (wid - 8) : (wid - 4);   // producer index 0..3

    if (wid == 0) {
        C2 tlo, thi;
        tri_solve128(ld2(wvA[lane]), ld2(weA[lane]), lane, tlo, thi);
        // P-Horner over tau_0..62 ; Q-Horner over tau_63..126 (interleaved chains)
        C2 pp = { rdlane(tlo.re, 0),  rdlane(tlo.im, 0)  };
        C2 dd = {0,0};
        C2 qq = { rdlane(tlo.re, 63), rdlane(tlo.im, 63) };   // tau_63
        C2 qd = {0,0};
        for (int i = 1; i <= 63; ++i) {
            if (i <= 62) {
                const C2 ti = { rdlane(tlo.re, i), rdlane(tlo.im, i) };
                dd = cadd(cmul(dd, g), pp);
                pp = cadd(cmul(pp, g), ti);
            }
            const C2 tq = { rdlane(thi.re, i-1), rdlane(thi.im, i-1) };  // tau_{63+i}
            qd = cadd(cmul(qd, g), qq);
            qq = cadd(cmul(qq, g), tq);
        }
        const C2 T64v = cmul(g, pp);              // T64(g)
        const C2 T64d = cadd(pp, cmul(g, dd));    // T64'(g)
        // T128(z) = z^64 T64(z) + z Q(z);  T128' = 64 z^63 T64 + z^64 T64' + Q + z Q'
        const C2 g63   = cmul(g64, cinv(g));
        const C2 T128v = cadd(cmul(g64, T64v), cmul(g, qq));
        const C2 T128d = cadd(cadd(cscale(64.0f, cmul(g63, T64v)), cmul(g64, T64d)),
                              cadd(qq, cmul(g, qd)));
        TgA[lane]  = st2(T64v);
        TpA[lane]  = st2(T64d);
        T1gA[lane] = st2(T128v);
        T1pA[lane] = st2(T128d);
    } else if (wid == 1) {
        float sg_re, sg_im;
        tri_solve64(ld2(wvA[lane]), ld2(avA[lane]), lane, sg_re, sg_im);   // sigma
        // X_0 = dB; X_{j+1} = g.*X_j + sigma_j * q
        C2 x = x0;
        for (int j = 0; j < 64; ++j) {
            Abuf[j*64 + ((lane + j) & 63)] = st2(x);
            const float sjr = rdlane(sg_re, j);
            const float sji = rdlane(sg_im, j);
            const float nr = g.re*x.re - g.im*x.im + sjr*q.re - sji*q.im;
            const float ni = g.re*x.im + g.im*x.re + sjr*q.im + sji*q.re;
            x.re = nr; x.im = ni;
        }
    } else if (wid == 12) {
        Cs[lane] = st2(Cv);                        // row 0: Y0_0 = C
    }
    __syncthreads();

    // ---------------- M build (closed form, power t = 64 or 128) ----------------
    // M_t[n][m] = d_nm g^t_n + q_n r_m [ (g^t_n - g^t_m) + (T_t(g_n)-T_t(g_m)) ] / (g_n - g_m)
    // M_t[n][n] = g^t_n + q_n r_n ( t g_n^{t-1} + T_t'(g_n) )
    C2 Mk[16];
    auto buildM = [&](bool p128){
        const C2 gt  = p128 ? cmul(g64, g64) : g64;                         // g^t (lane m)
        const C2 Ttm = p128 ? ld2(T1gA[lane]) : ld2(TgA[lane]);
        #pragma unroll
        for (int k = 0; k < 16; ++k) {
            const int n = 16*cw + k;
            const C2 gn   = ld2(gA[n]);            // uniform reads
            const C2 qn   = ld2(qA[n]);
            const C2 g64n = ld2(g64A[n]);
            const C2 gtn  = p128 ? cmul(g64n, g64n) : g64n;
            const C2 Ttn  = p128 ? ld2(T1gA[n]) : ld2(TgA[n]);
            const C2 idm  = cinv(csub(gn, g));     // n==lane -> inf/NaN, overwritten below
            const C2 num  = cmul(r, cadd(csub(gtn, gt), csub(Ttn, Ttm)));
            Mk[k] = cmul(cmul(qn, num), idm);
        }
        if ((lane >> 4) == cw) {                   // diagonal element owned by this thread
            const int k0 = lane & 15;
            const C2 Tp   = p128 ? ld2(T1pA[lane]) : ld2(TpA[lane]);
            const C2 g63  = cmul(g64, cinv(g));
            const C2 gtm1 = p128 ? cmul(g64, g63) : g63;      // g^{t-1}
            const C2 S    = cmul(r, cadd(cscale(p128 ? 128.0f : 64.0f, gtm1), Tp));
            Mk[k0] = cadd(gt, cmul(q, S));
        }
    };

    // matvec: acc[m] = sum_k Yin[16cw+k] * Mk[k][m], write partial
    auto chainStep = [&](const C2 Yin, int buf, int base){
        C2 acc = {0,0};
        #pragma unroll
        for (int k = 0; k < 16; ++k) {
            const float cr  = rdlane(Yin.re, 16*cw + k);
            const float cim = rdlane(Yin.im, 16*cw + k);
            acc.re += cr*Mk[k].re - cim*Mk[k].im;
            acc.im += cr*Mk[k].im + cim*Mk[k].re;
        }
        prt[buf*512 + base + cw*64 + lane] = st2(acc);
    };
    auto chainReduce = [&](int buf, int base) -> C2 {
        C2 nc = {0,0};
        #pragma unroll
        for (int w2 = 0; w2 < 4; ++w2) {
            const float2 pv = prt[buf*512 + base + w2*64 + lane];
            nc.re += pv.x; nc.im += pv.y;
        }
        return nc;
    };

    C2 Ci = Cv;
    // pre-step: chain B seeds Y1_0 = C . M64 (buf 0); chain A builds M128
    if (isB) {
        buildM(false);                  // M64 rows
        chainStep(Cv, 0, 256);
    } else if (isA) {
        buildM(true);                   // M128 rows
    }
    __syncthreads();
    if (isB) {
        Ci = chainReduce(0, 256);
        if (wid == 4) Cs[1*64 + lane] = st2(Ci);   // row 1
        buildM(true);                   // rebuild as M128
    }

    // main chain: steps s = 1..15
    for (int s = 1; s <= 15; ++s) {
        const int buf = s & 1;
        if (isA) chainStep(Ci, buf, 0);
        if (isB) chainStep(Ci, buf, 256);
        __syncthreads();
        if (isA) {
            Ci = chainReduce(buf, 0);
            if (wid == 8) Cs[(2*s)*64 + lane] = st2(Ci);       // even row
        }
        if (isB) {
            Ci = chainReduce(buf, 256);
            if (wid == 4) Cs[(2*s + 1)*64 + lane] = st2(Ci);   // odd row
        }
    }
    __syncthreads();

    // ---------------- output: rows r0 = 2*wid, r1 = 2*wid+1 ----------------
    {
        const int r0 = 2*wid, r1 = 2*wid + 1;
        float a0 = 0.0f, a1 = 0.0f;
        #pragma unroll 8
        for (int n = 0; n < 64; ++n) {
            const float2 xv = Abuf[lane*64 + ((n + lane) & 63)];
            const float2 c0 = Cs[r0*64 + n];    // uniform
            const float2 c1 = Cs[r1*64 + n];    // uniform
            a0 += c0.x*xv.x - c0.y*xv.y;
            a1 += c1.x*xv.x - c1.y*xv.y;
        }
        float* outh = out + h * LL;
        outh[r0*64 + lane] = 2.0f * a0;
        outh[r1*64 + lane] = 2.0f * a1;
    }
}

extern "C" void kernel_launch(void* const* d_in, const int* in_sizes, int n_in,
                              void* d_out, int out_size, void* d_ws, size_t ws_size,
                              hipStream_t stream) {
    const float* A_real = (const float*)d_in[0];
    const float* A_imag = (const float*)d_in[1];
    const float* B_real = (const float*)d_in[2];
    const float* B_imag = (const float*)d_in[3];
    const float* P_real = (const float*)d_in[4];
    const float* P_imag = (const float*)d_in[5];
    const float* C_real = (const float*)d_in[6];
    const float* C_imag = (const float*)d_in[7];
    const float* log_dt = (const float*)d_in[8];
    float* out = (float*)d_out;

    const size_t lds = 57344 + 13*64*sizeof(float2);   // 64000 B
    ssm_dplr_kernel<<<256, 1024, lds, stream>>>(
        A_real, A_imag, B_real, B_imag, P_real, P_imag,
        C_real, C_imag, log_dt, out);
}

// Round 7
// 108.192 us; speedup vs baseline: 1.1886x; 1.1790x over previous
//
#include <hip/hip_runtime.h>

// SSM DPLR kernel: K[h,l] = 2*Re(C_h . dA_h^l . dB_h), dA = diag(g) + q r^T.
// R10 (= R9 + scratch fix): the diagonal write Mk[k0] with k0=lane&15 was a
// RUNTIME index into a per-thread array -> compiler moved ALL of Mk[16] to
// scratch (R7-R9: FETCH/WRITE 2x inputs, VGPR_Count ~50, +20us). Fix: compute
// the diagonal value unconditionally and select it per-element inside the
// fully-unrolled k-loop (compile-time index, v_cndmask). Same arithmetic.
//   l = 64i + j: K[64i+j] = 2 Re( Y_i . X_j ), X_j = dA^j dB.
//   chain A (waves 8..11): Y0_i = C (M128)^i        -> even rows 2i
//   chain B (waves 4..7):  Y1_i = (C M64) (M128)^i  -> odd  rows 2i+1
//   16 barrier'd chain steps (1 seed + 15); ONE setup/serial window.
//   Serial window: wave0 tau128-solve + dual Horner; wave1 sigma+X.

#define LL 2048

struct C2 { float re, im; };

__device__ __forceinline__ C2 cmul(C2 a, C2 b){ return {a.re*b.re - a.im*b.im, a.re*b.im + a.im*b.re}; }
__device__ __forceinline__ C2 cadd(C2 a, C2 b){ return {a.re+b.re, a.im+b.im}; }
__device__ __forceinline__ C2 csub(C2 a, C2 b){ return {a.re-b.re, a.im-b.im}; }
__device__ __forceinline__ C2 cinv(C2 a){ float s=1.0f/(a.re*a.re+a.im*a.im); return {a.re*s, -a.im*s}; }
__device__ __forceinline__ C2 cscale(float s, C2 a){ return {s*a.re, s*a.im}; }
__device__ __forceinline__ C2 ld2(float2 v){ return {v.x, v.y}; }
__device__ __forceinline__ float2 st2(C2 v){ return make_float2(v.re, v.im); }

template<int CTRL>
__device__ __forceinline__ float dpp_add(float x){
  int t = __builtin_amdgcn_update_dpp(0, __float_as_int(x), CTRL, 0xF, 0xF, true);
  return x + __int_as_float(t);
}
// lane 63 ends with the full 64-lane sum
__device__ __forceinline__ float wave_sum63(float x){
  x = dpp_add<0xB1>(x);   // quad_perm xor1
  x = dpp_add<0x4E>(x);   // quad_perm xor2
  x = dpp_add<0x124>(x);  // row_ror:4
  x = dpp_add<0x128>(x);  // row_ror:8
  x = dpp_add<0x142>(x);  // row_bcast:15
  x = dpp_add<0x143>(x);  // row_bcast:31
  return x;
}
__device__ __forceinline__ float bcast63(float x){
  return __int_as_float(__builtin_amdgcn_readlane(__float_as_int(x), 63));
}
__device__ __forceinline__ float rdlane(float v, int l){
  return __int_as_float(__builtin_amdgcn_readlane(__float_as_int(v), l));
}
// D[m] = S[m-1], lane0 <- 0   (wave_shr:1 = 0x138)
__device__ __forceinline__ float shr1(float x){
  return __int_as_float(__builtin_amdgcn_update_dpp(0, __float_as_int(x), 0x138, 0xF, 0xF, true));
}
// insert scalar s (SGPR, from readlane) into lane 0 of v: v_cndmask
__device__ __forceinline__ float ins0(float v, float s, int lane){
  return (lane == 0) ? s : v;
}

// 2-wide triangular-Toeplitz solve (length 64): v_j = rhs_j + sum_{i<j} w_{j-1-i} v_i.
__device__ __forceinline__ void tri_solve64(const C2 wl, C2 va, const int lane,
                                            float& so_re, float& so_im)
{
    C2 wsh = { shr1(wl.re), shr1(wl.im) };      // w_{m-1}, lane0 = 0
    const float w0r = rdlane(wl.re, 0);
    const float w0i = rdlane(wl.im, 0);
    so_re = 0.0f; so_im = 0.0f;
    for (int j = 0; j < 64; j += 2) {
        const float s0r = rdlane(va.re, j);
        const float s0i = rdlane(va.im, j);
        const float v1r = rdlane(va.re, j + 1);
        const float v1i = rdlane(va.im, j + 1);
        const float s1r = v1r + (w0r*s0r - w0i*s0i);
        const float s1i = v1i + (w0r*s0i + w0i*s0r);
        if (lane == j)     { so_re = s0r; so_im = s0i; }
        if (lane == j + 1) { so_re = s1r; so_im = s1i; }
        const C2 wsh1 = { shr1(wsh.re), shr1(wsh.im) };   // w_{m-2-j}
        va.re += wsh.re*s0r - wsh.im*s0i;
        va.im += wsh.re*s0i + wsh.im*s0r;
        va.re += wsh1.re*s1r - wsh1.im*s1i;
        va.im += wsh1.re*s1i + wsh1.im*s1r;
        wsh.re = shr1(wsh1.re);
        wsh.im = shr1(wsh1.im);
    }
}

// 2-wide extended solve (length 128): state split lo (j=0..63) / hi (j=64..127).
// On return: tlo lane j = tau_j, thi lane c = tau_{64+c}.
__device__ __forceinline__ void tri_solve128(const C2 wlo, const C2 whi, const int lane,
                                             C2& tlo, C2& thi)
{
    C2 valo = wlo, vahi = whi;                  // rhs = w (tau solve)
    C2 wsl = { shr1(wlo.re), shr1(wlo.im) };    // w_{m-1}
    C2 wsh;                                     // w_{63+m'}
    {
        const float br = rdlane(wlo.re, 63), bi = rdlane(wlo.im, 63);
        wsh.re = ins0(shr1(whi.re), br, lane);
        wsh.im = ins0(shr1(whi.im), bi, lane);
    }
    const float w0r = rdlane(wlo.re, 0);
    const float w0i = rdlane(wlo.im, 0);
    tlo = {0,0}; thi = {0,0};
    // lo region: sources j = 0..63
    for (int j = 0; j < 64; j += 2) {
        const float s0r = rdlane(valo.re, j);
        const float s0i = rdlane(valo.im, j);
        const float v1r = rdlane(valo.re, j + 1);
        const float v1i = rdlane(valo.im, j + 1);
        const float s1r = v1r + (w0r*s0r - w0i*s0i);
        const float s1i = v1i + (w0r*s0i + w0i*s0r);
        if (lane == j)     { tlo.re = s0r; tlo.im = s0i; }
        if (lane == j + 1) { tlo.re = s1r; tlo.im = s1i; }
        // shifted coefficient registers for source j+1
        const C2 wsl1 = { shr1(wsl.re), shr1(wsl.im) };           // w_{m-2-j}
        C2 wsh1;
        {
            const float br = rdlane(wsl.re, 63), bi = rdlane(wsl.im, 63);  // w_{62-j}
            wsh1.re = ins0(shr1(wsh.re), br, lane);
            wsh1.im = ins0(shr1(wsh.im), bi, lane);
        }
        valo.re += wsl.re*s0r - wsl.im*s0i + wsl1.re*s1r - wsl1.im*s1i;
        valo.im += wsl.re*s0i + wsl.im*s0r + wsl1.re*s1i + wsl1.im*s1r;
        vahi.re += wsh.re*s0r - wsh.im*s0i + wsh1.re*s1r - wsh1.im*s1i;
        vahi.im += wsh.re*s0i + wsh.im*s0r + wsh1.re*s1i + wsh1.im*s1r;
        // advance by 2
        wsl.re = shr1(wsl1.re); wsl.im = shr1(wsl1.im);
        {
            const float br = rdlane(wsl1.re, 63), bi = rdlane(wsl1.im, 63); // w_{61-j}
            wsh.re = ins0(shr1(wsh1.re), br, lane);
            wsh.im = ins0(shr1(wsh1.im), bi, lane);
        }
    }
    // hi region: sources j = 64..127; lo coefficients exhausted, shift-ins are 0.
    for (int j = 64; j < 128; j += 2) {
        const int jr = j - 64;
        const float s0r = rdlane(vahi.re, jr);
        const float s0i = rdlane(vahi.im, jr);
        const float v1r = rdlane(vahi.re, jr + 1);
        const float v1i = rdlane(vahi.im, jr + 1);
        const float s1r = v1r + (w0r*s0r - w0i*s0i);
        const float s1i = v1i + (w0r*s0i + w0i*s0r);
        if (lane == jr)     { thi.re = s0r; thi.im = s0i; }
        if (lane == jr + 1) { thi.re = s1r; thi.im = s1i; }
        const C2 wsh1 = { shr1(wsh.re), shr1(wsh.im) };
        vahi.re += wsh.re*s0r - wsh.im*s0i + wsh1.re*s1r - wsh1.im*s1i;
        vahi.im += wsh.re*s0i + wsh.im*s0r + wsh1.re*s1i + wsh1.im*s1r;
        wsh.re = shr1(wsh1.re);
        wsh.im = shr1(wsh1.im);
    }
}

__global__ __launch_bounds__(1024)
__attribute__((amdgpu_waves_per_eu(4, 4)))
void ssm_dplr_kernel(
    const float* __restrict__ A_real, const float* __restrict__ A_imag,
    const float* __restrict__ B_real, const float* __restrict__ B_imag,
    const float* __restrict__ P_real, const float* __restrict__ P_imag,
    const float* __restrict__ C_real, const float* __restrict__ C_imag,
    const float* __restrict__ log_dt, float* __restrict__ out)
{
    const int h    = blockIdx.x;
    const int t    = threadIdx.x;
    const int lane = t & 63;
    const int wid  = t >> 6;         // wave 0..15

    extern __shared__ char sm[];
    float2* Abuf = (float2*)sm;               // 64x64: G (powers), later X  [32 KB]
    float2* Cs   = (float2*)(sm + 32768);     // 32x64 Y rows                [16 KB]
    float2* prt  = (float2*)(sm + 49152);     // 2 x (8x64) chain partials   [ 8 KB]
    // transpose-sum partials alias Cs + prt (dead at that phase):
    float2* tw   = (float2*)(sm + 32768);     // 16x64
    float2* ta   = (float2*)(sm + 40960);     // 16x64
    float2* te   = (float2*)(sm + 49152);     // 16x64 (= prt, dead then)
    float2* gA   = (float2*)(sm + 57344);     // smalls, 64 float2 each:
    float2* qA   = gA + 64;
    float2* g64A = gA + 128;
    float2* TgA  = gA + 192;   // T64(g)
    float2* TpA  = gA + 256;   // T64'(g)
    float2* T1gA = gA + 320;   // T128(g)
    float2* T1pA = gA + 384;   // T128'(g)
    float2* rqA  = gA + 448;
    float2* rxA  = gA + 512;
    float2* reA  = gA + 576;   // rq * g64
    float2* wvA  = gA + 640;   // w_0..63
    float2* avA  = gA + 704;   // a_0..63
    float2* weA  = gA + 768;   // w_64..127
    // LDS total: 57344 + 13*512 = 64000 B  (<= 64 KB dynamic limit)

    // ---------------- setup (every wave redundantly, per-lane n = lane) ----------------
    const int idx = h * 64 + lane;
    const float dt = expf(log_dt[h]);
    const float c  = 0.5f * dt;

    const C2 lam = { -A_real[idx], -A_imag[idx] };
    const C2 p   = {  P_real[idx],  P_imag[idx] };
    const C2 Bv  = {  B_real[idx],  B_imag[idx] };
    const C2 Cv  = {  C_real[idx],  C_imag[idx] };
    const C2 pc  = { p.re, -p.im };

    const C2 d = cinv(C2{ 1.0f - c*lam.re, -c*lam.im });
    const C2 g = cmul(d, C2{ 1.0f + c*lam.re, c*lam.im });   // diag of dA

    // Sherman-Morrison scalars via DPP wave sums
    C2 sv = cscale(p.re*p.re + p.im*p.im, d);
    C2 uv = cmul(cmul(d, pc), Bv);
    sv.re = bcast63(wave_sum63(sv.re)); sv.im = bcast63(wave_sum63(sv.im));
    uv.re = bcast63(wave_sum63(uv.re)); uv.im = bcast63(wave_sum63(uv.im));

    const C2 beta  = cscale(c, cinv(C2{ 1.0f + c*sv.re, c*sv.im }));
    const C2 bs    = cmul(beta, sv);
    const C2 gamma = { -c*(1.0f - bs.re), c*bs.im };

    const C2 q  = cmul(d, p);
    const C2 r  = cmul(pc, csub(gamma, cmul(beta, g)));
    const C2 x0 = cscale(dt, csub(cmul(d, Bv), cmul(cmul(beta, uv), q)));  // dB

    // power chain
    const C2 g2  = cmul(g,  g);
    const C2 g4  = cmul(g2, g2);
    const C2 g8  = cmul(g4, g4);
    const C2 g16 = cmul(g8, g8);
    const C2 g32 = cmul(g16,g16);
    const C2 g64 = cmul(g32,g32);

    if (wid == 0) {
        const C2 rq = cmul(r, q);
        gA[lane]   = st2(g);
        qA[lane]   = st2(q);
        g64A[lane] = st2(g64);
        rqA[lane]  = st2(rq);
        rxA[lane]  = st2(cmul(r, x0));
        reA[lane]  = st2(cmul(rq, g64));
    }
    __syncthreads();

    // ---------------- G-gen: G[j][n] = g_n^j, rows j in [4w, 4w+4) ----------------
    {
        C2 cur = {1.0f, 0.0f};
        if (wid & 1) cur = g4;
        if (wid & 2) cur = cmul(cur, g8);
        if (wid & 4) cur = cmul(cur, g16);
        if (wid & 8) cur = cmul(cur, g32);          // g^(4*wid)
        #pragma unroll
        for (int jj = 0; jj < 4; ++jj) {
            const int j = 4*wid + jj;
            Abuf[j*64 + ((lane + j) & 63)] = st2(cur);   // rotated columns
            cur = cmul(cur, g);
        }
    }
    __syncthreads();

    // ---------------- w_j, a_j, we_j (=w_{64+j}) via transpose-sum (lane = j) ----------------
    {
        C2 accw = {0,0}, acca = {0,0}, acce = {0,0};
        #pragma unroll
        for (int kk = 0; kk < 4; ++kk) {
            const int n = 4*wid + kk;
            const C2 Gv = ld2(Abuf[lane*64 + ((n + lane) & 63)]);
            const C2 fq = ld2(rqA[n]);      // uniform
            const C2 fx = ld2(rxA[n]);      // uniform
            const C2 fe = ld2(reA[n]);      // uniform
            accw = cadd(accw, cmul(Gv, fq));
            acca = cadd(acca, cmul(Gv, fx));
            acce = cadd(acce, cmul(Gv, fe));
        }
        tw[wid*64 + lane] = st2(accw);
        ta[wid*64 + lane] = st2(acca);
        te[wid*64 + lane] = st2(acce);
    }
    __syncthreads();
    if (t < 64) {
        C2 sw = {0,0}, sa = {0,0}, se = {0,0};
        #pragma unroll
        for (int w2 = 0; w2 < 16; ++w2) {
            sw = cadd(sw, ld2(tw[w2*64 + t]));
            sa = cadd(sa, ld2(ta[w2*64 + t]));
            se = cadd(se, ld2(te[w2*64 + t]));
        }
        wvA[t] = st2(sw);
        avA[t] = st2(sa);
        weA[t] = st2(se);
    }
    __syncthreads();

    // ---------------- serial window ----------------
    // wave0: tau-solve (length 128) + dual Horner -> T64/T64'/T128/T128'
    // wave1: sigma-solve + X rebuild;  wave12: seed Cs[0]=C
    const bool isB = (wid >= 4 && wid < 8);    // chain B: odd rows, seeds with M64
    const bool isA = (wid >= 8 && wid < 12);   // chain A: even rows
    const int  cw  = isA ? (wid - 8) : (wid - 4);   // producer index 0..3

    if (wid == 0) {
        C2 tlo, thi;
        tri_solve128(ld2(wvA[lane]), ld2(weA[lane]), lane, tlo, thi);
        // P-Horner over tau_0..62 ; Q-Horner over tau_63..126 (interleaved chains)
        C2 pp = { rdlane(tlo.re, 0),  rdlane(tlo.im, 0)  };
        C2 dd = {0,0};
        C2 qq = { rdlane(tlo.re, 63), rdlane(tlo.im, 63) };   // tau_63
        C2 qd = {0,0};
        for (int i = 1; i <= 63; ++i) {
            if (i <= 62) {
                const C2 ti = { rdlane(tlo.re, i), rdlane(tlo.im, i) };
                dd = cadd(cmul(dd, g), pp);
                pp = cadd(cmul(pp, g), ti);
            }
            const C2 tq = { rdlane(thi.re, i-1), rdlane(thi.im, i-1) };  // tau_{63+i}
            qd = cadd(cmul(qd, g), qq);
            qq = cadd(cmul(qq, g), tq);
        }
        const C2 T64v = cmul(g, pp);              // T64(g)
        const C2 T64d = cadd(pp, cmul(g, dd));    // T64'(g)
        // T128(z) = z^64 T64(z) + z Q(z);  T128' = 64 z^63 T64 + z^64 T64' + Q + z Q'
        const C2 g63   = cmul(g64, cinv(g));
        const C2 T128v = cadd(cmul(g64, T64v), cmul(g, qq));
        const C2 T128d = cadd(cadd(cscale(64.0f, cmul(g63, T64v)), cmul(g64, T64d)),
                              cadd(qq, cmul(g, qd)));
        TgA[lane]  = st2(T64v);
        TpA[lane]  = st2(T64d);
        T1gA[lane] = st2(T128v);
        T1pA[lane] = st2(T128d);
    } else if (wid == 1) {
        float sg_re, sg_im;
        tri_solve64(ld2(wvA[lane]), ld2(avA[lane]), lane, sg_re, sg_im);   // sigma
        // X_0 = dB; X_{j+1} = g.*X_j + sigma_j * q
        C2 x = x0;
        for (int j = 0; j < 64; ++j) {
            Abuf[j*64 + ((lane + j) & 63)] = st2(x);
            const float sjr = rdlane(sg_re, j);
            const float sji = rdlane(sg_im, j);
            const float nr = g.re*x.re - g.im*x.im + sjr*q.re - sji*q.im;
            const float ni = g.re*x.im + g.im*x.re + sjr*q.im + sji*q.re;
            x.re = nr; x.im = ni;
        }
    } else if (wid == 12) {
        Cs[lane] = st2(Cv);                        // row 0: Y0_0 = C
    }
    __syncthreads();

    // ---------------- M build (closed form, power t = 64 or 128) ----------------
    // M_t[n][m] = d_nm g^t_n + q_n r_m [ (g^t_n - g^t_m) + (T_t(g_n)-T_t(g_m)) ] / (g_n - g_m)
    // M_t[n][n] = g^t_n + q_n r_n ( t g_n^{t-1} + T_t'(g_n) )
    // Diagonal handled via per-element SELECT with compile-time k (NO runtime
    // array index -> Mk stays in VGPRs).
    C2 Mk[16];
    auto buildM = [&](bool p128){
        const C2 gt  = p128 ? cmul(g64, g64) : g64;                         // g^t (lane m)
        const C2 Ttm = p128 ? ld2(T1gA[lane]) : ld2(TgA[lane]);
        // diagonal value for the element this lane owns (valid when ownRow)
        const C2 Tp    = p128 ? ld2(T1pA[lane]) : ld2(TpA[lane]);
        const C2 g63   = cmul(g64, cinv(g));
        const C2 gtm1  = p128 ? cmul(g64, g63) : g63;          // g^{t-1}
        const C2 S     = cmul(r, cadd(cscale(p128 ? 128.0f : 64.0f, gtm1), Tp));
        const C2 diagv = cadd(gt, cmul(q, S));
        const bool ownRow = ((lane >> 4) == cw);
        #pragma unroll
        for (int k = 0; k < 16; ++k) {
            const int n = 16*cw + k;
            const C2 gn   = ld2(gA[n]);            // uniform reads
            const C2 qn   = ld2(qA[n]);
            const C2 g64n = ld2(g64A[n]);
            const C2 gtn  = p128 ? cmul(g64n, g64n) : g64n;
            const C2 Ttn  = p128 ? ld2(T1gA[n]) : ld2(TgA[n]);
            const C2 idm  = cinv(csub(gn, g));     // n==lane -> inf/NaN, deselected below
            const C2 num  = cmul(r, cadd(csub(gtn, gt), csub(Ttn, Ttm)));
            const C2 off  = cmul(cmul(qn, num), idm);
            const bool isd = ownRow && ((lane & 15) == k);     // k is compile-time
            Mk[k].re = isd ? diagv.re : off.re;
            Mk[k].im = isd ? diagv.im : off.im;
        }
    };

    // matvec: acc[m] = sum_k Yin[16cw+k] * Mk[k][m], write partial
    auto chainStep = [&](const C2 Yin, int buf, int base){
        C2 acc = {0,0};
        #pragma unroll
        for (int k = 0; k < 16; ++k) {
            const float cr  = rdlane(Yin.re, 16*cw + k);
            const float cim = rdlane(Yin.im, 16*cw + k);
            acc.re += cr*Mk[k].re - cim*Mk[k].im;
            acc.im += cr*Mk[k].im + cim*Mk[k].re;
        }
        prt[buf*512 + base + cw*64 + lane] = st2(acc);
    };
    auto chainReduce = [&](int buf, int base) -> C2 {
        C2 nc = {0,0};
        #pragma unroll
        for (int w2 = 0; w2 < 4; ++w2) {
            const float2 pv = prt[buf*512 + base + w2*64 + lane];
            nc.re += pv.x; nc.im += pv.y;
        }
        return nc;
    };

    C2 Ci = Cv;
    // pre-step: chain B seeds Y1_0 = C . M64 (buf 0); chain A builds M128
    if (isB) {
        buildM(false);                  // M64 rows
        chainStep(Cv, 0, 256);
    } else if (isA) {
        buildM(true);                   // M128 rows
    }
    __syncthreads();
    if (isB) {
        Ci = chainReduce(0, 256);
        if (wid == 4) Cs[1*64 + lane] = st2(Ci);   // row 1
        buildM(true);                   // rebuild as M128
    }

    // main chain: steps s = 1..15
    for (int s = 1; s <= 15; ++s) {
        const int buf = s & 1;
        if (isA) chainStep(Ci, buf, 0);
        if (isB) chainStep(Ci, buf, 256);
        __syncthreads();
        if (isA) {
            Ci = chainReduce(buf, 0);
            if (wid == 8) Cs[(2*s)*64 + lane] = st2(Ci);       // even row
        }
        if (isB) {
            Ci = chainReduce(buf, 256);
            if (wid == 4) Cs[(2*s + 1)*64 + lane] = st2(Ci);   // odd row
        }
    }
    __syncthreads();

    // ---------------- output: rows r0 = 2*wid, r1 = 2*wid+1 ----------------
    {
        const int r0 = 2*wid, r1 = 2*wid + 1;
        float a0 = 0.0f, a1 = 0.0f;
        #pragma unroll 8
        for (int n = 0; n < 64; ++n) {
            const float2 xv = Abuf[lane*64 + ((n + lane) & 63)];
            const float2 c0 = Cs[r0*64 + n];    // uniform
            const float2 c1 = Cs[r1*64 + n];    // uniform
            a0 += c0.x*xv.x - c0.y*xv.y;
            a1 += c1.x*xv.x - c1.y*xv.y;
        }
        float* outh = out + h * LL;
        outh[r0*64 + lane] = 2.0f * a0;
        outh[r1*64 + lane] = 2.0f * a1;
    }
}

extern "C" void kernel_launch(void* const* d_in, const int* in_sizes, int n_in,
                              void* d_out, int out_size, void* d_ws, size_t ws_size,
                              hipStream_t stream) {
    const float* A_real = (const float*)d_in[0];
    const float* A_imag = (const float*)d_in[1];
    const float* B_real = (const float*)d_in[2];
    const float* B_imag = (const float*)d_in[3];
    const float* P_real = (const float*)d_in[4];
    const float* P_imag = (const float*)d_in[5];
    const float* C_real = (const float*)d_in[6];
    const float* C_imag = (const float*)d_in[7];
    const float* log_dt = (const float*)d_in[8];
    float* out = (float*)d_out;

    const size_t lds = 57344 + 13*64*sizeof(float2);   // 64000 B
    ssm_dplr_kernel<<<256, 1024, lds, stream>>>(
        A_real, A_imag, B_real, B_imag, P_real, P_imag,
        C_real, C_imag, log_dt, out);
}